// Round 1
// baseline (540.829 us; speedup 1.0000x reference)
//
#include <hip/hip_runtime.h>

// RelativePositionEncoding: B=1, N=1024, C_Z=128
// W rows: [0..65]=W_res, [66..131]=W_tok, [132]=w_ent, [133..138]=W_chain
// Output p[i][j][c] = W_res[dr] + W_tok[dt] + same_ent*w_ent + W_chain[dc]
// Fold: same_ent <=> dc<=4, so chain2[c] = W_chain[c] + (c<5 ? w_ent : 0)
//   => p = W_res[dr] + W_tok[dt] + chain2[dc]

#define NPOS 1024
#define CZ4 32           // 128 floats = 32 float4
#define SROWS 138        // 66 res + 66 tok + 6 folded chain

__global__ __launch_bounds__(1024, 8)
void relpos_kernel(const int* __restrict__ asym,
                   const int* __restrict__ resi,
                   const int* __restrict__ ent,
                   const int* __restrict__ sym,
                   const int* __restrict__ tok,
                   const float4* __restrict__ W4,
                   float4* __restrict__ out)
{
    __shared__ float4 sW[SROWS * CZ4];   // 70,656 B -> 2 blocks/CU

    const int tid = threadIdx.x;

    // Stage W into LDS, skipping the w_ent row and folding it into chain rows 0..4.
    for (int idx = tid; idx < SROWS * CZ4; idx += 1024) {
        int row = idx >> 5;
        int c4  = idx & 31;
        int src = (row < 132) ? row : row + 1;   // sW rows 132..137 <- W rows 133..138
        float4 v = W4[src * CZ4 + c4];
        if (row >= 132 && row <= 136) {          // chain idx 0..4: same_ent true -> add w_ent
            float4 e = W4[132 * CZ4 + c4];
            v.x += e.x; v.y += e.y; v.z += e.z; v.w += e.w;
        }
        sW[idx] = v;
    }
    __syncthreads();

    const int c4    = tid & 31;        // float4 index within the 128-float channel dim
    const int group = tid >> 5;        // 0..31: which pair this 32-lane group handles
    const int stride = gridDim.x * 32;

    for (int p = blockIdx.x * 32 + group; p < NPOS * NPOS; p += stride) {
        const int i = p >> 10;
        const int j = p & (NPOS - 1);

        const int ai = asym[i], aj = asym[j];
        const int ri = resi[i], rj = resi[j];
        const int ei = ent[i],  ej = ent[j];
        const int si = sym[i],  sj = sym[j];
        const int ti = tok[i],  tj = tok[j];

        const bool same_chain = (ai == aj);
        const bool same_res   = (ri == rj);
        const bool same_ent   = (ei == ej);

        const int dr = same_chain              ? min(max(ri - rj + 32, 0), 64) : 65;
        const int dt = (same_chain && same_res)? min(max(ti - tj + 32, 0), 64) : 65;
        const int dc = same_ent                ? min(max(si - sj + 2, 0), 4)   : 5;

        const float4 a = sW[dr * CZ4 + c4];
        const float4 b = sW[(66 + dt) * CZ4 + c4];
        const float4 c = sW[(132 + dc) * CZ4 + c4];

        float4 v;
        v.x = a.x + b.x + c.x;
        v.y = a.y + b.y + c.y;
        v.z = a.z + b.z + c.z;
        v.w = a.w + b.w + c.w;

        out[(size_t)p * CZ4 + c4] = v;
    }
}

extern "C" void kernel_launch(void* const* d_in, const int* in_sizes, int n_in,
                              void* d_out, int out_size, void* d_ws, size_t ws_size,
                              hipStream_t stream) {
    const int*    asym = (const int*)d_in[0];
    const int*    resi = (const int*)d_in[1];
    const int*    ent  = (const int*)d_in[2];
    const int*    sym  = (const int*)d_in[3];
    const int*    tok  = (const int*)d_in[4];
    const float4* W4   = (const float4*)d_in[5];
    float4*       out  = (float4*)d_out;

    // 512 blocks x 1024 threads: exactly 2 blocks/CU resident on 256 CUs,
    // grid-stride covers 1,048,576 pairs in 64 clean iterations.
    relpos_kernel<<<512, 1024, 0, stream>>>(asym, resi, ent, sym, tok, W4, out);
}

// Round 2
// 529.401 us; speedup vs baseline: 1.0216x; 1.0216x over previous
//
#include <hip/hip_runtime.h>

// RelativePositionEncoding: B=1, N=1024, C_Z=128, FEAT=139
// W rows: [0..65]=W_res, [66..131]=W_tok, [132]=w_ent, [133..138]=W_chain
// p[i][j][:] = W_res[dr] + W_tok[dt] + same_ent*w_ent + W_chain[dc]
// Fold: same_ent <=> dc<=4, so sW rows 132..137 = W_chain[0..5] + (dc<5 ? w_ent : 0)

typedef float f4 __attribute__((ext_vector_type(4)));

#define NPOS 1024
#define CZ4 32            // 128 floats = 32 float4
#define SROWS 138         // 66 res + 66 tok + 6 folded chain
#define ROWS_PER_BLK 2    // each block owns 2 output rows i

__global__ __launch_bounds__(1024, 8)
void relpos_kernel(const int* __restrict__ asym,
                   const int* __restrict__ resi,
                   const int* __restrict__ ent,
                   const int* __restrict__ sym,
                   const int* __restrict__ tok,
                   const f4* __restrict__ W4,
                   f4* __restrict__ out)
{
    __shared__ f4  sW[SROWS * CZ4];            // 70,656 B
    __shared__ int codes[ROWS_PER_BLK * NPOS]; // 8,192 B  (total 78,848 -> 2 blk/CU)

    const int tid = threadIdx.x;
    const int i0  = blockIdx.x * ROWS_PER_BLK;

    // ---- Phase 0: stage W into LDS, folding w_ent into chain rows 0..4 ----
    for (int idx = tid; idx < SROWS * CZ4; idx += 1024) {
        int row = idx >> 5;
        int c4  = idx & 31;
        int src = (row < 132) ? row : row + 1;   // skip w_ent row
        f4 v = W4[src * CZ4 + c4];
        if (row >= 132 && row <= 136) {          // chain idx 0..4: same_ent true
            v += W4[132 * CZ4 + c4];
        }
        sW[idx] = v;
    }

    // ---- Phase 1: per-(i,j) packed codes, computed ONCE per pair ----
    #pragma unroll
    for (int r = 0; r < ROWS_PER_BLK; ++r) {
        const int i = i0 + r;                    // same addr for all threads -> broadcast
        const int j = tid;                       // coalesced dword loads
        const int ai = asym[i], aj = asym[j];
        const int ri = resi[i], rj = resi[j];
        const int ei = ent[i],  ej = ent[j];
        const int si = sym[i],  sj = sym[j];
        const int ti = tok[i],  tj = tok[j];

        const bool same_chain = (ai == aj);
        const bool same_res   = (ri == rj);
        const bool same_ent   = (ei == ej);

        const int dr = same_chain               ? min(max(ri - rj + 32, 0), 64) : 65;
        const int dt = (same_chain && same_res) ? min(max(ti - tj + 32, 0), 64) : 65;
        const int dc = same_ent                 ? min(max(si - sj + 2, 0), 4)   : 5;

        codes[r * NPOS + j] = dr | (dt << 7) | (dc << 14);
    }
    __syncthreads();

    // ---- Phase 2: stream 128-float rows to HBM ----
    const int c4 = tid & 31;        // float4 lane within channel dim
    const int g  = tid >> 5;        // 0..31: pair-group
    const size_t obase = (size_t)i0 * NPOS * CZ4;

    #pragma unroll 2
    for (int it = 0; it < (ROWS_PER_BLK * NPOS) / 32; ++it) {
        const int p    = it * 32 + g;            // local pair index in [0, 2048)
        const int code = codes[p];               // broadcast ds_read_b32
        const int dr   = code & 127;
        const int dt   = (code >> 7) & 127;
        const int dc   = code >> 14;

        f4 v = sW[dr * CZ4 + c4];
        v += sW[(66 + dt) * CZ4 + c4];
        v += sW[(132 + dc) * CZ4 + c4];

        __builtin_nontemporal_store(v, &out[obase + (size_t)p * CZ4 + c4]);
    }
}

extern "C" void kernel_launch(void* const* d_in, const int* in_sizes, int n_in,
                              void* d_out, int out_size, void* d_ws, size_t ws_size,
                              hipStream_t stream) {
    const int* asym = (const int*)d_in[0];
    const int* resi = (const int*)d_in[1];
    const int* ent  = (const int*)d_in[2];
    const int* sym  = (const int*)d_in[3];
    const int* tok  = (const int*)d_in[4];
    const f4*  W4   = (const f4*)d_in[5];
    f4*        out  = (f4*)d_out;

    // 512 blocks x 1024 threads, 2 rows each: all blocks co-resident (2/CU),
    // each block writes one contiguous 1 MB output region.
    relpos_kernel<<<NPOS / ROWS_PER_BLK, 1024, 0, stream>>>(asym, resi, ent, sym, tok, W4, out);
}